// Round 5
// baseline (240.682 us; speedup 1.0000x reference)
//
#include <hip/hip_runtime.h>

#define DEVI __device__ __forceinline__

typedef short short4_t __attribute__((ext_vector_type(4)));
typedef short short8_t __attribute__((ext_vector_type(8)));
typedef __bf16 bf16x8 __attribute__((ext_vector_type(8)));
typedef float f32x4 __attribute__((ext_vector_type(4)));

// float -> bf16 bits, round-to-nearest-even
DEVI short f2bf(float f) {
    union { float f; unsigned u; } v; v.f = f;
    unsigned r = (v.u + 0x7fffu + ((v.u >> 16) & 1u)) >> 16;
    return (short)r;
}

// pack two floats to packed bf16 (round-half-up): one add each + one v_perm
DEVI unsigned pack_ru(float a, float b) {
    union { float f; unsigned u; } x, y; x.f = a; y.f = b;
    return __builtin_amdgcn_perm(y.u + 0x8000u, x.u + 0x8000u, 0x07060302u);
}

// K=16 bf16 MFMA: D = A(16x16)*B(16x16)+C.  A[m=lane&15][k=quad*4+j], B[k=quad*4+j][n=lane&15].
DEVI f32x4 pv_mfma(short4_t a, short4_t b, f32x4 c) {
#if defined(__HIP_DEVICE_COMPILE__)
#if __has_builtin(__builtin_amdgcn_mfma_f32_16x16x16bf16_1k)
    return __builtin_amdgcn_mfma_f32_16x16x16bf16_1k(a, b, c, 0, 0, 0);
#else
    union { short8_t s; bf16x8 b; } ua, ub;
    ua.s = (short8_t){a[0], a[1], a[2], a[3], 0, 0, 0, 0};
    ub.s = (short8_t){b[0], b[1], b[2], b[3], 0, 0, 0, 0};
    return __builtin_amdgcn_mfma_f32_16x16x32_bf16(ua.b, ub.b, c, 0, 0, 0);
#endif
#else
    (void)a; (void)b;
    return c;
#endif
}

// async global->LDS, 16B per lane; lds dest must be wave-uniform base (+lane*16 implicit)
DEVI void g2lds16(const short* g, short* l) {
    __builtin_amdgcn_global_load_lds(
        (const __attribute__((address_space(1))) void*)g,
        (__attribute__((address_space(3))) void*)l, 16, 0, 0);
}

// ---------------- convert q,k,v fp32 -> bf16 concatenated [12288,1024] ----------------
__global__ __launch_bounds__(256) void cvt3_kernel(const float* __restrict__ q,
                                                   const float* __restrict__ k,
                                                   const float* __restrict__ v,
                                                   short* __restrict__ X) {
    const size_t N1 = (size_t)4096 * 1024;
    size_t e = ((size_t)blockIdx.x * 256 + threadIdx.x) * 4;
    const float* src; size_t off;
    if (e < N1)            { src = q; off = e; }
    else if (e < 2 * N1)   { src = k; off = e - N1; }
    else                   { src = v; off = e - 2 * N1; }
    f32x4 f = *(const f32x4*)(src + off);
    short4_t o;
    o[0] = f2bf(f[0]); o[1] = f2bf(f[1]); o[2] = f2bf(f[2]); o[3] = f2bf(f[3]);
    *(short4_t*)(X + e) = o;
}

// ---------------- W [1024][1024] fp32 row-major [k][n] -> Wt bf16 [n][k] ----------------
__global__ __launch_bounds__(256) void transpose_w_kernel(const float* __restrict__ W,
                                                          short* __restrict__ Wt) {
    __shared__ short T[64][65];
    const int t = threadIdx.x;
    const int kt = blockIdx.x * 64, nt = blockIdx.y * 64;
#pragma unroll
    for (int r = 0; r < 4; ++r) {
        int kl = (t >> 4) + 16 * r;
        int n0 = (t & 15) * 4;
        f32x4 f = *(const f32x4*)(W + (size_t)(kt + kl) * 1024 + nt + n0);
#pragma unroll
        for (int j = 0; j < 4; ++j) T[n0 + j][kl] = f2bf(f[j]);
    }
    __syncthreads();
#pragma unroll
    for (int r = 0; r < 2; ++r) {
        int nl = (t >> 3) + 32 * r;
        int k0 = (t & 7) * 8;
        short8_t v;
#pragma unroll
        for (int j = 0; j < 8; ++j) v[j] = T[nl][k0 + j];
        *(short8_t*)(Wt + (size_t)(nt + nl) * 1024 + kt + k0) = v;
    }
}

// ---------------- GEMM 128x128  C[M][N] = A[M][K]*Bt[N][K]^T + bias ----------------
template <typename OutT>
__global__ __launch_bounds__(256) void gemm_bt_kernel(const short* __restrict__ A,
                                                      const short* __restrict__ Bt,
                                                      const float* __restrict__ bias,
                                                      OutT* __restrict__ C,
                                                      int M, int N, int K,
                                                      int qrows, float qscale) {
    __shared__ __align__(16) short As[128 * 32];
    __shared__ __align__(16) short Bs[128 * 32];
    const int tid  = threadIdx.x;
    const int lane = tid & 63, wave = tid >> 6;
    const int quad = lane >> 4, l16 = lane & 15;
    const int row0 = blockIdx.x * 128, col0 = blockIdx.y * 128;
    const int wm = (wave >> 1) * 64, wn = (wave & 1) * 64;
    const int srow = lane >> 2;
    const int scol = (lane & 3) * 8;
    f32x4 acc[4][4] = {};
    for (int k0 = 0; k0 < K; k0 += 32) {
#pragma unroll
        for (int r = 0; r < 2; ++r) {
            int rb = r * 64 + wave * 16;
            g2lds16(A  + (size_t)(row0 + rb + srow) * K + k0 + scol, &As[rb * 32]);
            g2lds16(Bt + (size_t)(col0 + rb + srow) * K + k0 + scol, &Bs[rb * 32]);
        }
        __syncthreads();
        bf16x8 af[4], bfr[4];
#pragma unroll
        for (int mi = 0; mi < 4; ++mi) af[mi]  = *(const bf16x8*)&As[(wm + mi * 16 + l16) * 32 + quad * 8];
#pragma unroll
        for (int ni = 0; ni < 4; ++ni) bfr[ni] = *(const bf16x8*)&Bs[(wn + ni * 16 + l16) * 32 + quad * 8];
#pragma unroll
        for (int mi = 0; mi < 4; ++mi)
#pragma unroll
            for (int ni = 0; ni < 4; ++ni)
                acc[mi][ni] = __builtin_amdgcn_mfma_f32_16x16x32_bf16(af[mi], bfr[ni], acc[mi][ni], 0, 0, 0);
        __syncthreads();
    }
#pragma unroll
    for (int mi = 0; mi < 4; ++mi) {
#pragma unroll
        for (int ni = 0; ni < 4; ++ni) {
            int col = col0 + wn + ni * 16 + l16;
            float bv = bias[col];
#pragma unroll
            for (int i = 0; i < 4; ++i) {
                int row = row0 + wm + mi * 16 + quad * 4 + i;
                float val = acc[mi][ni][i] + bv;
                if (row < qrows) val *= qscale;
                if constexpr (sizeof(OutT) == 2) C[(size_t)row * N + col] = (OutT)f2bf(val);
                else                             C[(size_t)row * N + col] = (OutT)val;
            }
        }
    }
}

// ---------------- GEMM 64x128 tiles (2 blocks/CU at grid 512) ----------------
__global__ __launch_bounds__(256) void gemm_bt64_kernel(const short* __restrict__ A,
                                                        const short* __restrict__ Bt,
                                                        const float* __restrict__ bias,
                                                        float* __restrict__ C,
                                                        int M, int N, int K) {
    __shared__ __align__(16) short As[64 * 32];
    __shared__ __align__(16) short Bs[128 * 32];
    const int tid  = threadIdx.x;
    const int lane = tid & 63, wave = tid >> 6;
    const int quad = lane >> 4, l16 = lane & 15;
    const int row0 = blockIdx.x * 64, col0 = blockIdx.y * 128;
    const int wn = wave * 32;
    const int srow = lane >> 2;
    const int scol = (lane & 3) * 8;
    f32x4 acc[4][2] = {};
    for (int k0 = 0; k0 < K; k0 += 32) {
        {
            int rb = wave * 16;
            g2lds16(A + (size_t)(row0 + rb + srow) * K + k0 + scol, &As[rb * 32]);
        }
#pragma unroll
        for (int r = 0; r < 2; ++r) {
            int rb = r * 64 + wave * 16;
            g2lds16(Bt + (size_t)(col0 + rb + srow) * K + k0 + scol, &Bs[rb * 32]);
        }
        __syncthreads();
        bf16x8 af[4], bfr[2];
#pragma unroll
        for (int mi = 0; mi < 4; ++mi) af[mi]  = *(const bf16x8*)&As[(mi * 16 + l16) * 32 + quad * 8];
#pragma unroll
        for (int ni = 0; ni < 2; ++ni) bfr[ni] = *(const bf16x8*)&Bs[(wn + ni * 16 + l16) * 32 + quad * 8];
#pragma unroll
        for (int mi = 0; mi < 4; ++mi)
#pragma unroll
            for (int ni = 0; ni < 2; ++ni)
                acc[mi][ni] = __builtin_amdgcn_mfma_f32_16x16x32_bf16(af[mi], bfr[ni], acc[mi][ni], 0, 0, 0);
        __syncthreads();
    }
#pragma unroll
    for (int mi = 0; mi < 4; ++mi) {
#pragma unroll
        for (int ni = 0; ni < 2; ++ni) {
            int col = col0 + wn + ni * 16 + l16;
            float bv = bias[col];
#pragma unroll
            for (int i = 0; i < 4; ++i) {
                int row = row0 + mi * 16 + quad * 4 + i;
                C[(size_t)row * N + col] = acc[mi][ni][i] + bv;
            }
        }
    }
}

// ---------------- P_v [b*2048+s][1024] head slice -> VT[(h*2+b)*64+d][2048] ----------------
__global__ __launch_bounds__(256) void transpose_v_kernel(const short* __restrict__ Pv,
                                                          short* __restrict__ VT) {
    __shared__ short T[64][65];
    const int t = threadIdx.x;
    const int hb = blockIdx.x, st = blockIdx.y * 64;
    const int h = hb >> 1, b = hb & 1;
#pragma unroll
    for (int r = 0; r < 2; ++r) {
        int sl = (t >> 3) + 32 * r;
        short8_t v = *(const short8_t*)(Pv + (size_t)(b * 2048 + st + sl) * 1024 + h * 64 + (t & 7) * 8);
#pragma unroll
        for (int j = 0; j < 8; ++j) T[(t & 7) * 8 + j][sl] = v[j];
    }
    __syncthreads();
#pragma unroll
    for (int r = 0; r < 2; ++r) {
        int dl = (t >> 3) + 32 * r;
        short8_t v;
#pragma unroll
        for (int j = 0; j < 8; ++j) v[j] = T[dl][(t & 7) * 8 + j];
        *(short8_t*)(VT + ((size_t)hb * 64 + dl) * 2048 + st + (t & 7) * 8) = v;
    }
}

// ---------------- flash attention v4: 2-way KV split, fp32 partial numerators ----------------
// P rows 0..4095 = Q proj (PRESCALED by inv_scale*log2e), 4096..8191 = K proj
__global__ __launch_bounds__(256) void attn_kernel(const short* __restrict__ P,
                                                   const short* __restrict__ VT,
                                                   float* __restrict__ Onum0,
                                                   float* __restrict__ Onum1,
                                                   float* __restrict__ lpart) {
    constexpr int LDK = 72;   // 144B rows, conflict-free b128 frag reads
    constexpr int LDV = 136;  // 272B rows, conflict-free b64 frag reads
    constexpr int LDOF = 68;  // fp32 epilogue transpose stride
    union SmemU {
        struct { short Ks[2][128 * LDK]; short Vs[2][64 * LDV]; } s;
        float OTf[256 * LDOF];
    };
    __shared__ __align__(16) SmemU sm;

    const int t = threadIdx.x;
    const int lane = t & 63, wave = t >> 6;
    const int quad = lane >> 4, l16 = lane & 15;
    // grid 512: xcd = bx&7; each XCD owns 4 hb (both kv-splits + all qt of those hb)
    const int bx = blockIdx.x;
    const int xcd = bx & 7, idx = bx >> 3;
    const int hb = xcd * 4 + (idx & 3);
    const int rest = idx >> 2;              // 0..15
    const int qt = rest & 7, split = rest >> 3;
    const int h = hb >> 1, b = hb & 1;
    const int kvbase = split * 1024;
    const short* Pq  = P + (size_t)(b * 2048 + qt * 256) * 1024 + h * 64;
    const short* Pk  = P + (size_t)(4096 + b * 2048 + kvbase) * 1024 + h * 64;
    const short* VTh = VT + (size_t)hb * 64 * 2048 + kvbase;
    const int wq = wave * 64;

    // Q fragments: 64 q rows/wave, registers for the whole KV loop (B-operand layout)
    bf16x8 qf[4][2];
#pragma unroll
    for (int miq = 0; miq < 4; ++miq)
#pragma unroll
        for (int kh = 0; kh < 2; ++kh)
            qf[miq][kh] = *(const bf16x8*)(Pq + (size_t)(wq + miq * 16 + l16) * 1024 + kh * 32 + quad * 8);

    float lrow[4] = {0.f, 0.f, 0.f, 0.f};
    f32x4 oacc[4][4] = {};   // [di][miq], O^T C-layout: d=quad*4+i, q=l16

    const int krow = t >> 3, kc8 = (t & 7) * 8;    // K stage: 32 rows/pass x 4
    const int vrow = t >> 4, vc8 = (t & 15) * 8;   // V stage: 16 rows/pass x 4

    short8_t kreg[4], vreg[4];
#pragma unroll
    for (int it = 0; it < 4; ++it) {
        kreg[it] = *(const short8_t*)(Pk + (size_t)(it * 32 + krow) * 1024 + kc8);
        vreg[it] = *(const short8_t*)(VTh + (size_t)(it * 16 + vrow) * 2048 + vc8);
    }

    for (int tile = 0; tile < 8; ++tile) {
        const int buf = tile & 1;
        short* Ksb = sm.s.Ks[buf];
        short* Vsb = sm.s.Vs[buf];
#pragma unroll
        for (int it = 0; it < 4; ++it) {
            *(short8_t*)&Ksb[(it * 32 + krow) * LDK + kc8] = kreg[it];
            *(short8_t*)&Vsb[(it * 16 + vrow) * LDV + vc8] = vreg[it];
        }
        __syncthreads();
        if (tile + 1 < 8) {   // prefetch overlaps the whole compute phase below
            int kv0 = (tile + 1) * 128;
#pragma unroll
            for (int it = 0; it < 4; ++it) {
                kreg[it] = *(const short8_t*)(Pk + (size_t)(kv0 + it * 32 + krow) * 1024 + kc8);
                vreg[it] = *(const short8_t*)(VTh + (size_t)(it * 16 + vrow) * 2048 + kv0 + vc8);
            }
        }
#pragma unroll
        for (int kvc = 0; kvc < 8; ++kvc) {
            // S^T = K Q^T : A = K rows (kv), B = Q (in regs)
            bf16x8 a0 = *(const bf16x8*)&Ksb[(kvc * 16 + l16) * LDK + quad * 8];
            bf16x8 a1 = *(const bf16x8*)&Ksb[(kvc * 16 + l16) * LDK + 32 + quad * 8];
            // V^T A-frags (k=16 MFMA): lane d=l16, k=quad*4+j
            short4_t vA[4];
#pragma unroll
            for (int di = 0; di < 4; ++di)
                vA[di] = *(const short4_t*)&Vsb[(di * 16 + l16) * LDV + kvc * 16 + quad * 4];
#pragma unroll
            for (int miq = 0; miq < 4; ++miq) {
                f32x4 s = {};
                s = __builtin_amdgcn_mfma_f32_16x16x32_bf16(a0, qf[miq][0], s, 0, 0, 0);
                s = __builtin_amdgcn_mfma_f32_16x16x32_bf16(a1, qf[miq][1], s, 0, 0, 0);
                float p0 = __builtin_amdgcn_exp2f(s[0]);
                float p1 = __builtin_amdgcn_exp2f(s[1]);
                float p2 = __builtin_amdgcn_exp2f(s[2]);
                float p3 = __builtin_amdgcn_exp2f(s[3]);
                lrow[miq] += (p0 + p1) + (p2 + p3);
                union { uint2 u; short4_t s4; } pb;
                pb.u.x = pack_ru(p0, p1);
                pb.u.y = pack_ru(p2, p3);
                // O^T += V^T * P : C-frag of S^T is exactly the k=16 B-operand layout
#pragma unroll
                for (int di = 0; di < 4; ++di)
                    oacc[di][miq] = pv_mfma(vA[di], pb.s4, oacc[di][miq]);
            }
        }
        __syncthreads();
    }

    float* Onum = split ? Onum1 : Onum0;
    // partial row sums -> lpart (all lanes end with the full sum; quad 0 stores)
#pragma unroll
    for (int miq = 0; miq < 4; ++miq) {
        float ls = lrow[miq];
        ls += __shfl_xor(ls, 16);
        ls += __shfl_xor(ls, 32);
        if (quad == 0) {
            int row = b * 2048 + qt * 256 + wq + miq * 16 + l16;
            lpart[(size_t)split * 65536 + row * 16 + h] = ls;
        }
    }
    __syncthreads();   // all Ks/Vs reads done before OTf aliases them

    // raw numerator O^T -> LDS fp32 transpose, then contiguous 256B/thread store
#pragma unroll
    for (int di = 0; di < 4; ++di) {
#pragma unroll
        for (int miq = 0; miq < 4; ++miq) {
            int q = wq + miq * 16 + l16;
            *(f32x4*)&sm.OTf[q * LDOF + di * 16 + quad * 4] = oacc[di][miq];
        }
    }
    __syncthreads();
    {
        float* dst = Onum + (size_t)(b * 2048 + qt * 256 + t) * 1024 + h * 64;
#pragma unroll
        for (int c = 0; c < 16; ++c)
            *(f32x4*)(dst + c * 4) = *(const f32x4*)&sm.OTf[t * LDOF + c * 4];
    }
}

// ---------------- combine: O = bf16((N0+N1)/(l0+l1)) ----------------
__global__ __launch_bounds__(256) void combine_kernel(const float* __restrict__ n0,
                                                      const float* __restrict__ n1,
                                                      const float* __restrict__ lp,
                                                      short* __restrict__ O) {
    size_t e = ((size_t)blockIdx.x * 256 + threadIdx.x) * 4;
    int row = (int)(e >> 10);
    int hh = ((int)e >> 6) & 15;
    float l = lp[(size_t)row * 16 + hh] + lp[65536 + (size_t)row * 16 + hh];
    float r = 1.0f / l;
    f32x4 a = *(const f32x4*)(n0 + e);
    f32x4 b = *(const f32x4*)(n1 + e);
    short4_t o;
#pragma unroll
    for (int i = 0; i < 4; ++i) o[i] = f2bf((a[i] + b[i]) * r);
    *(short4_t*)(O + e) = o;
}

extern "C" void kernel_launch(void* const* d_in, const int* in_sizes, int n_in,
                              void* d_out, int out_size, void* d_ws, size_t ws_size,
                              hipStream_t stream) {
    (void)in_sizes; (void)n_in; (void)out_size; (void)ws_size;
    const float* q  = (const float*)d_in[0];
    const float* k  = (const float*)d_in[1];
    const float* v  = (const float*)d_in[2];
    const float* Wq = (const float*)d_in[3];
    const float* bq = (const float*)d_in[4];
    const float* Wo = (const float*)d_in[5];
    const float* bo = (const float*)d_in[6];
    float* out = (float*)d_out;

    short* Xcat = (short*)d_ws;                        // [12288][1024] bf16 (dead after gemm1)
    short* WqT  = Xcat + (size_t)12288 * 1024;         // [1024][1024]      (dead after gemm1)
    short* WoT  = WqT + (size_t)1024 * 1024;           // [1024][1024]
    short* P    = WoT + (size_t)1024 * 1024;           // [12288][1024] (q|k|v projections)
    short* VT   = P + (size_t)12288 * 1024;            // [32][64][2048]
    short* O    = VT + (size_t)32 * 64 * 2048;         // [4096][1024]
    float* Onum0 = (float*)Xcat;                       // 16.8MB aliases Xcat (attn phase)
    float* lpart = (float*)WqT;                        // 0.5MB aliases WqT  (attn phase)
    float* Onum1 = (float*)(O + (size_t)4096 * 1024);  // fresh 16.8MB

    // softmax scale * log2(e), folded into Q rows of the projection GEMM
    const float qscale = 0.022097086912079608f * 1.4426950408889634f;

    cvt3_kernel<<<12288, 256, 0, stream>>>(q, k, v, Xcat);
    transpose_w_kernel<<<dim3(16, 16), 256, 0, stream>>>(Wq, WqT);
    transpose_w_kernel<<<dim3(16, 16), 256, 0, stream>>>(Wo, WoT);
    gemm_bt_kernel<short><<<dim3(96, 8), 256, 0, stream>>>(Xcat, WqT, bq, P, 12288, 1024, 1024, 4096, qscale);
    transpose_v_kernel<<<dim3(32, 32), 256, 0, stream>>>(P + (size_t)8192 * 1024, VT);
    attn_kernel<<<512, 256, 0, stream>>>(P, VT, Onum0, Onum1, lpart);
    combine_kernel<<<4096, 256, 0, stream>>>(Onum0, Onum1, lpart, O);
    gemm_bt64_kernel<<<dim3(64, 8), 256, 0, stream>>>(O, WoT, bo, out, 4096, 1024, 1024);
}

// Round 6
// 219.777 us; speedup vs baseline: 1.0951x; 1.0951x over previous
//
#include <hip/hip_runtime.h>

#define DEVI __device__ __forceinline__

typedef short short4_t __attribute__((ext_vector_type(4)));
typedef short short8_t __attribute__((ext_vector_type(8)));
typedef __bf16 bf16x8 __attribute__((ext_vector_type(8)));
typedef float f32x4 __attribute__((ext_vector_type(4)));

// float -> bf16 bits, round-to-nearest-even
DEVI short f2bf(float f) {
    union { float f; unsigned u; } v; v.f = f;
    unsigned r = (v.u + 0x7fffu + ((v.u >> 16) & 1u)) >> 16;
    return (short)r;
}

// pack two floats to packed bf16 (round-half-up): one add each + one v_perm
DEVI unsigned pack_ru(float a, float b) {
    union { float f; unsigned u; } x, y; x.f = a; y.f = b;
    return __builtin_amdgcn_perm(y.u + 0x8000u, x.u + 0x8000u, 0x07060302u);
}

// K=16 bf16 MFMA: D = A(16x16)*B(16x16)+C.  A[m=lane&15][k=quad*4+j], B[k=quad*4+j][n=lane&15].
DEVI f32x4 pv_mfma(short4_t a, short4_t b, f32x4 c) {
#if defined(__HIP_DEVICE_COMPILE__)
#if __has_builtin(__builtin_amdgcn_mfma_f32_16x16x16bf16_1k)
    return __builtin_amdgcn_mfma_f32_16x16x16bf16_1k(a, b, c, 0, 0, 0);
#else
    union { short8_t s; bf16x8 b; } ua, ub;
    ua.s = (short8_t){a[0], a[1], a[2], a[3], 0, 0, 0, 0};
    ub.s = (short8_t){b[0], b[1], b[2], b[3], 0, 0, 0, 0};
    return __builtin_amdgcn_mfma_f32_16x16x32_bf16(ua.b, ub.b, c, 0, 0, 0);
#endif
#else
    (void)a; (void)b;
    return c;
#endif
}

// async global->LDS, 16B per lane; lds dest must be wave-uniform base (+lane*16 implicit)
DEVI void g2lds16(const short* g, short* l) {
    __builtin_amdgcn_global_load_lds(
        (const __attribute__((address_space(1))) void*)g,
        (__attribute__((address_space(3))) void*)l, 16, 0, 0);
}

// ---------------- convert q,k,v fp32 -> bf16 concatenated [12288,1024] ----------------
__global__ __launch_bounds__(256) void cvt3_kernel(const float* __restrict__ q,
                                                   const float* __restrict__ k,
                                                   const float* __restrict__ v,
                                                   short* __restrict__ X) {
    const size_t N1 = (size_t)4096 * 1024;
    size_t e = ((size_t)blockIdx.x * 256 + threadIdx.x) * 4;
    const float* src; size_t off;
    if (e < N1)            { src = q; off = e; }
    else if (e < 2 * N1)   { src = k; off = e - N1; }
    else                   { src = v; off = e - 2 * N1; }
    f32x4 f = *(const f32x4*)(src + off);
    short4_t o;
    o[0] = f2bf(f[0]); o[1] = f2bf(f[1]); o[2] = f2bf(f[2]); o[3] = f2bf(f[3]);
    *(short4_t*)(X + e) = o;
}

// ---------------- W [1024][1024] fp32 row-major [k][n] -> Wt bf16 [n][k] ----------------
__global__ __launch_bounds__(256) void transpose_w_kernel(const float* __restrict__ W,
                                                          short* __restrict__ Wt) {
    __shared__ short T[64][65];
    const int t = threadIdx.x;
    const int kt = blockIdx.x * 64, nt = blockIdx.y * 64;
#pragma unroll
    for (int r = 0; r < 4; ++r) {
        int kl = (t >> 4) + 16 * r;
        int n0 = (t & 15) * 4;
        f32x4 f = *(const f32x4*)(W + (size_t)(kt + kl) * 1024 + nt + n0);
#pragma unroll
        for (int j = 0; j < 4; ++j) T[n0 + j][kl] = f2bf(f[j]);
    }
    __syncthreads();
#pragma unroll
    for (int r = 0; r < 2; ++r) {
        int nl = (t >> 3) + 32 * r;
        int k0 = (t & 7) * 8;
        short8_t v;
#pragma unroll
        for (int j = 0; j < 8; ++j) v[j] = T[nl][k0 + j];
        *(short8_t*)(Wt + (size_t)(nt + nl) * 1024 + kt + k0) = v;
    }
}

// ---------------- GEMM 128x128  C[M][N] = A[M][K]*Bt[N][K]^T + bias ----------------
template <typename OutT>
__global__ __launch_bounds__(256) void gemm_bt_kernel(const short* __restrict__ A,
                                                      const short* __restrict__ Bt,
                                                      const float* __restrict__ bias,
                                                      OutT* __restrict__ C,
                                                      int M, int N, int K,
                                                      int qrows, float qscale) {
    __shared__ __align__(16) short As[128 * 32];
    __shared__ __align__(16) short Bs[128 * 32];
    const int tid  = threadIdx.x;
    const int lane = tid & 63, wave = tid >> 6;
    const int quad = lane >> 4, l16 = lane & 15;
    const int row0 = blockIdx.x * 128, col0 = blockIdx.y * 128;
    const int wm = (wave >> 1) * 64, wn = (wave & 1) * 64;
    const int srow = lane >> 2;
    const int scol = (lane & 3) * 8;
    f32x4 acc[4][4] = {};
    for (int k0 = 0; k0 < K; k0 += 32) {
#pragma unroll
        for (int r = 0; r < 2; ++r) {
            int rb = r * 64 + wave * 16;
            g2lds16(A  + (size_t)(row0 + rb + srow) * K + k0 + scol, &As[rb * 32]);
            g2lds16(Bt + (size_t)(col0 + rb + srow) * K + k0 + scol, &Bs[rb * 32]);
        }
        __syncthreads();
        bf16x8 af[4], bfr[4];
#pragma unroll
        for (int mi = 0; mi < 4; ++mi) af[mi]  = *(const bf16x8*)&As[(wm + mi * 16 + l16) * 32 + quad * 8];
#pragma unroll
        for (int ni = 0; ni < 4; ++ni) bfr[ni] = *(const bf16x8*)&Bs[(wn + ni * 16 + l16) * 32 + quad * 8];
#pragma unroll
        for (int mi = 0; mi < 4; ++mi)
#pragma unroll
            for (int ni = 0; ni < 4; ++ni)
                acc[mi][ni] = __builtin_amdgcn_mfma_f32_16x16x32_bf16(af[mi], bfr[ni], acc[mi][ni], 0, 0, 0);
        __syncthreads();
    }
#pragma unroll
    for (int mi = 0; mi < 4; ++mi) {
#pragma unroll
        for (int ni = 0; ni < 4; ++ni) {
            int col = col0 + wn + ni * 16 + l16;
            float bv = bias[col];
#pragma unroll
            for (int i = 0; i < 4; ++i) {
                int row = row0 + wm + mi * 16 + quad * 4 + i;
                float val = acc[mi][ni][i] + bv;
                if (row < qrows) val *= qscale;
                if constexpr (sizeof(OutT) == 2) C[(size_t)row * N + col] = (OutT)f2bf(val);
                else                             C[(size_t)row * N + col] = (OutT)val;
            }
        }
    }
}

// ---------------- GEMM 64x128 tiles (more blocks/CU for the small output GEMM) ----------------
__global__ __launch_bounds__(256) void gemm_bt64_kernel(const short* __restrict__ A,
                                                        const short* __restrict__ Bt,
                                                        const float* __restrict__ bias,
                                                        float* __restrict__ C,
                                                        int M, int N, int K) {
    __shared__ __align__(16) short As[64 * 32];
    __shared__ __align__(16) short Bs[128 * 32];
    const int tid  = threadIdx.x;
    const int lane = tid & 63, wave = tid >> 6;
    const int quad = lane >> 4, l16 = lane & 15;
    const int row0 = blockIdx.x * 64, col0 = blockIdx.y * 128;
    const int wn = wave * 32;
    const int srow = lane >> 2;
    const int scol = (lane & 3) * 8;
    f32x4 acc[4][2] = {};
    for (int k0 = 0; k0 < K; k0 += 32) {
        {
            int rb = wave * 16;
            g2lds16(A + (size_t)(row0 + rb + srow) * K + k0 + scol, &As[rb * 32]);
        }
#pragma unroll
        for (int r = 0; r < 2; ++r) {
            int rb = r * 64 + wave * 16;
            g2lds16(Bt + (size_t)(col0 + rb + srow) * K + k0 + scol, &Bs[rb * 32]);
        }
        __syncthreads();
        bf16x8 af[4], bfr[2];
#pragma unroll
        for (int mi = 0; mi < 4; ++mi) af[mi]  = *(const bf16x8*)&As[(mi * 16 + l16) * 32 + quad * 8];
#pragma unroll
        for (int ni = 0; ni < 2; ++ni) bfr[ni] = *(const bf16x8*)&Bs[(wn + ni * 16 + l16) * 32 + quad * 8];
#pragma unroll
        for (int mi = 0; mi < 4; ++mi)
#pragma unroll
            for (int ni = 0; ni < 2; ++ni)
                acc[mi][ni] = __builtin_amdgcn_mfma_f32_16x16x32_bf16(af[mi], bfr[ni], acc[mi][ni], 0, 0, 0);
        __syncthreads();
    }
#pragma unroll
    for (int mi = 0; mi < 4; ++mi) {
#pragma unroll
        for (int ni = 0; ni < 2; ++ni) {
            int col = col0 + wn + ni * 16 + l16;
            float bv = bias[col];
#pragma unroll
            for (int i = 0; i < 4; ++i) {
                int row = row0 + mi * 16 + quad * 4 + i;
                C[(size_t)row * N + col] = acc[mi][ni][i] + bv;
            }
        }
    }
}

// ---------------- P_v [b*2048+s][1024] head slice -> VT[(h*2+b)*64+d][2048] ----------------
__global__ __launch_bounds__(256) void transpose_v_kernel(const short* __restrict__ Pv,
                                                          short* __restrict__ VT) {
    __shared__ short T[64][65];
    const int t = threadIdx.x;
    const int hb = blockIdx.x, st = blockIdx.y * 64;
    const int h = hb >> 1, b = hb & 1;
#pragma unroll
    for (int r = 0; r < 2; ++r) {
        int sl = (t >> 3) + 32 * r;
        short8_t v = *(const short8_t*)(Pv + (size_t)(b * 2048 + st + sl) * 1024 + h * 64 + (t & 7) * 8);
#pragma unroll
        for (int j = 0; j < 8; ++j) T[(t & 7) * 8 + j][sl] = v[j];
    }
    __syncthreads();
#pragma unroll
    for (int r = 0; r < 2; ++r) {
        int dl = (t >> 3) + 32 * r;
        short8_t v;
#pragma unroll
        for (int j = 0; j < 8; ++j) v[j] = T[dl][(t & 7) * 8 + j];
        *(short8_t*)(VT + ((size_t)hb * 64 + dl) * 2048 + st + (t & 7) * 8) = v;
    }
}

// ---------------- flash attention v5: 512 threads (8 waves = 2/SIMD), q-tile 256 ----------------
// P rows 0..4095 = Q proj (PRESCALED by inv_scale*log2e), 4096..8191 = K proj
__global__ __launch_bounds__(512, 2) void attn_kernel(const short* __restrict__ P,
                                                      const short* __restrict__ VT,
                                                      short* __restrict__ O) {
    constexpr int LDK = 72;   // 144B rows, b128 frag reads uniform over banks
    constexpr int LDV = 136;  // 272B rows, b64 frag reads uniform over banks
    constexpr int LDO = 72;   // epilogue transpose stride
    union SmemU {
        struct { short Ks[2][128 * LDK]; short Vs[2][64 * LDV]; } s;
        short OT[256 * LDO];
    };
    __shared__ __align__(16) SmemU sm;

    const int t = threadIdx.x;
    const int lane = t & 63, wave = t >> 6;      // 8 waves
    const int quad = lane >> 4, l16 = lane & 15;
    // XCD swizzle: 256 blocks, xcd = bx&7 -> each XCD owns 4 hb (K/V slices fit its L2)
    const int bx = blockIdx.x;
    const int xcd = bx & 7, bi = bx >> 3;
    const int hb = xcd * 4 + (bi & 3), qt = bi >> 2;   // hb 0..31, qt 0..7 (256-row q tiles)
    const int h = hb >> 1, b = hb & 1;
    const short* Pq  = P + (size_t)(b * 2048 + qt * 256) * 1024 + h * 64;
    const short* Pk  = P + (size_t)(4096 + b * 2048) * 1024 + h * 64;
    const short* VTh = VT + (size_t)hb * 64 * 2048;
    const int wq = wave * 32;   // 32 q rows per wave

    // Q fragments: registers for the whole KV loop (B-operand layout = Q rows)
    bf16x8 qf[2][2];
#pragma unroll
    for (int miq = 0; miq < 2; ++miq)
#pragma unroll
        for (int kh = 0; kh < 2; ++kh)
            qf[miq][kh] = *(const bf16x8*)(Pq + (size_t)(wq + miq * 16 + l16) * 1024 + kh * 32 + quad * 8);

    float lrow[2] = {0.f, 0.f};
    f32x4 oacc[4][2] = {};   // [di][miq], O^T C-layout: d=quad*4+i, q=l16

    const int krow = t >> 3, kc8 = (t & 7) * 8;    // K stage: 64 rows/pass x 2
    const int vrow = t >> 4, vc8 = (t & 15) * 8;   // V stage: 32 rows/pass x 2

    short8_t kreg[2], vreg[2];
#pragma unroll
    for (int it = 0; it < 2; ++it) {
        kreg[it] = *(const short8_t*)(Pk + (size_t)(it * 64 + krow) * 1024 + kc8);
        vreg[it] = *(const short8_t*)(VTh + (size_t)(it * 32 + vrow) * 2048 + vc8);
    }

    for (int tile = 0; tile < 16; ++tile) {
        const int buf = tile & 1;
        short* Ksb = sm.s.Ks[buf];
        short* Vsb = sm.s.Vs[buf];
#pragma unroll
        for (int it = 0; it < 2; ++it) {
            *(short8_t*)&Ksb[(it * 64 + krow) * LDK + kc8] = kreg[it];
            *(short8_t*)&Vsb[(it * 32 + vrow) * LDV + vc8] = vreg[it];
        }
        __syncthreads();
        if (tile + 1 < 16) {   // prefetch overlaps the whole compute phase below
            int kv0 = (tile + 1) * 128;
#pragma unroll
            for (int it = 0; it < 2; ++it) {
                kreg[it] = *(const short8_t*)(Pk + (size_t)(kv0 + it * 64 + krow) * 1024 + kc8);
                vreg[it] = *(const short8_t*)(VTh + (size_t)(it * 32 + vrow) * 2048 + kv0 + vc8);
            }
        }
#pragma unroll
        for (int kvc = 0; kvc < 8; ++kvc) {
            // S^T = K Q^T : A = K rows (kv), B = Q (in regs)
            bf16x8 a0 = *(const bf16x8*)&Ksb[(kvc * 16 + l16) * LDK + quad * 8];
            bf16x8 a1 = *(const bf16x8*)&Ksb[(kvc * 16 + l16) * LDK + 32 + quad * 8];
            // V^T A-frags (k=16 MFMA): lane d=l16, k=quad*4+j
            short4_t vA[4];
#pragma unroll
            for (int di = 0; di < 4; ++di)
                vA[di] = *(const short4_t*)&Vsb[(di * 16 + l16) * LDV + kvc * 16 + quad * 4];
#pragma unroll
            for (int miq = 0; miq < 2; ++miq) {
                f32x4 s = {};
                s = __builtin_amdgcn_mfma_f32_16x16x32_bf16(a0, qf[miq][0], s, 0, 0, 0);
                s = __builtin_amdgcn_mfma_f32_16x16x32_bf16(a1, qf[miq][1], s, 0, 0, 0);
                float p0 = __builtin_amdgcn_exp2f(s[0]);
                float p1 = __builtin_amdgcn_exp2f(s[1]);
                float p2 = __builtin_amdgcn_exp2f(s[2]);
                float p3 = __builtin_amdgcn_exp2f(s[3]);
                lrow[miq] += (p0 + p1) + (p2 + p3);
                union { uint2 u; short4_t s4; } pb;
                pb.u.x = pack_ru(p0, p1);
                pb.u.y = pack_ru(p2, p3);
                // O^T += V^T * P : C-frag of S^T is exactly the k=16 B-operand layout
#pragma unroll
                for (int di = 0; di < 4; ++di)
                    oacc[di][miq] = pv_mfma(vA[di], pb.s4, oacc[di][miq]);
            }
        }
        __syncthreads();
    }

    // full row sums: lane's lrow covers its quad's kv rows -> reduce across quad bits
    float rinv[2];
#pragma unroll
    for (int miq = 0; miq < 2; ++miq) {
        float ls = lrow[miq];
        ls += __shfl_xor(ls, 16);
        ls += __shfl_xor(ls, 32);
        rinv[miq] = 1.0f / ls;   // aligned with O^T cols (q=l16)
    }
    // loop's final __syncthreads: all Ks/Vs reads done -> OT may alias them

    // O^T -> LDS (bf16, b64 uniform banks), then coalesced row-major store
#pragma unroll
    for (int di = 0; di < 4; ++di) {
#pragma unroll
        for (int miq = 0; miq < 2; ++miq) {
            float v0 = oacc[di][miq][0] * rinv[miq];
            float v1 = oacc[di][miq][1] * rinv[miq];
            float v2 = oacc[di][miq][2] * rinv[miq];
            float v3 = oacc[di][miq][3] * rinv[miq];
            uint2 w;
            w.x = pack_ru(v0, v1);
            w.y = pack_ru(v2, v3);
            int q = wq + miq * 16 + l16;
            *(uint2*)&sm.OT[q * LDO + di * 16 + quad * 4] = w;
        }
    }
    __syncthreads();
    {
        const int orow = t >> 1, ocol = (t & 1) * 32;
        short* dst = O + (size_t)(b * 2048 + qt * 256 + orow) * 1024 + h * 64 + ocol;
#pragma unroll
        for (int c = 0; c < 4; ++c)
            *(short8_t*)(dst + c * 8) = *(const short8_t*)&sm.OT[orow * LDO + ocol + c * 8];
    }
}

extern "C" void kernel_launch(void* const* d_in, const int* in_sizes, int n_in,
                              void* d_out, int out_size, void* d_ws, size_t ws_size,
                              hipStream_t stream) {
    (void)in_sizes; (void)n_in; (void)out_size; (void)ws_size;
    const float* q  = (const float*)d_in[0];
    const float* k  = (const float*)d_in[1];
    const float* v  = (const float*)d_in[2];
    const float* Wq = (const float*)d_in[3];
    const float* bq = (const float*)d_in[4];
    const float* Wo = (const float*)d_in[5];
    const float* bo = (const float*)d_in[6];
    float* out = (float*)d_out;

    short* Xcat = (short*)d_ws;                        // [12288][1024] bf16
    short* WqT  = Xcat + (size_t)12288 * 1024;         // [1024][1024]
    short* WoT  = WqT + (size_t)1024 * 1024;           // [1024][1024]
    short* P    = WoT + (size_t)1024 * 1024;           // [12288][1024] (q|k|v projections)
    short* VT   = P + (size_t)12288 * 1024;            // [32][64][2048]
    short* O    = VT + (size_t)32 * 64 * 2048;         // [4096][1024]

    // softmax scale * log2(e), folded into Q rows of the projection GEMM
    const float qscale = 0.022097086912079608f * 1.4426950408889634f;

    cvt3_kernel<<<12288, 256, 0, stream>>>(q, k, v, Xcat);
    transpose_w_kernel<<<dim3(16, 16), 256, 0, stream>>>(Wq, WqT);
    transpose_w_kernel<<<dim3(16, 16), 256, 0, stream>>>(Wo, WoT);
    gemm_bt_kernel<short><<<dim3(96, 8), 256, 0, stream>>>(Xcat, WqT, bq, P, 12288, 1024, 1024, 4096, qscale);
    transpose_v_kernel<<<dim3(32, 32), 256, 0, stream>>>(P + (size_t)8192 * 1024, VT);
    attn_kernel<<<256, 512, 0, stream>>>(P, VT, O);
    gemm_bt64_kernel<<<dim3(64, 8), 256, 0, stream>>>(O, WoT, bo, out, 4096, 1024, 1024);
}